// Round 1
// baseline (2374.456 us; speedup 1.0000x reference)
//
#include <hip/hip_runtime.h>

#define N_NODES_C 100000
#define N_EDGES_C 3200000
#define IN_F_C 10
#define HID_C 64
#define N_CLS_C 10
#define NEG_SLOPE_C 0.01f

// ---------------- degree / dinv ----------------
__global__ __launch_bounds__(256) void k_deg_init(float* deg, int n) {
    int i = blockIdx.x * blockDim.x + threadIdx.x;
    if (i < n) deg[i] = 1.0f;  // self loop
}

__global__ __launch_bounds__(256) void k_deg_scatter(const int* __restrict__ dst, float* deg, int E) {
    for (int e = blockIdx.x * blockDim.x + threadIdx.x; e < E; e += gridDim.x * blockDim.x)
        atomicAdd(&deg[dst[e]], 1.0f);
}

__global__ __launch_bounds__(256) void k_deg_fin(float* deg, int n) {
    int i = blockIdx.x * blockDim.x + threadIdx.x;
    if (i < n) deg[i] = rsqrtf(deg[i]);
}

// ---------------- matmul + dinv scale: hs[n,f] = (sum_k hin[n,k] W[k,f]) * dinv[n] ----------------
template <int K>
__global__ __launch_bounds__(256) void k_mm_scale(const float* __restrict__ hin,
                                                  const float* __restrict__ W,
                                                  const float* __restrict__ dinv,
                                                  float* __restrict__ hs, int n) {
    __shared__ float Ws[K * HID_C];
    for (int i = threadIdx.x; i < K * HID_C; i += blockDim.x) Ws[i] = W[i];
    __syncthreads();
    int total = n * HID_C;
    for (int t = blockIdx.x * blockDim.x + threadIdx.x; t < total; t += gridDim.x * blockDim.x) {
        int nn = t >> 6;          // HID_C == 64
        int f  = t & 63;
        const float* row = hin + (long long)nn * K;
        float s = 0.f;
#pragma unroll
        for (int k = 0; k < K; ++k) s += row[k] * Ws[k * HID_C + f];
        hs[t] = s * dinv[nn];
    }
}

// ---------------- edge scatter: acc[dst] += hs[src], one wave per edge ----------------
__global__ __launch_bounds__(256) void k_scatter(const int* __restrict__ src,
                                                 const int* __restrict__ dst,
                                                 const float* __restrict__ hs,
                                                 float* __restrict__ acc, int E) {
    int lane = threadIdx.x & 63;
    long long w  = (long long)(blockIdx.x * blockDim.x + threadIdx.x) >> 6;
    long long nw = ((long long)gridDim.x * blockDim.x) >> 6;
    for (long long e = w; e < E; e += nw) {
        int s = src[e];
        int d = dst[e];
        float v = hs[((long long)s << 6) + lane];
        atomicAdd(acc + ((long long)d << 6) + lane, v);
    }
}

// ---------------- epilogue: act = lrelu((acc + hs) * dinv + b), in place into acc ----------------
__global__ __launch_bounds__(256) void k_act(float* __restrict__ acc,
                                             const float* __restrict__ hs,
                                             const float* __restrict__ dinv,
                                             const float* __restrict__ b, int n) {
    int total = n * HID_C;
    for (int t = blockIdx.x * blockDim.x + threadIdx.x; t < total; t += gridDim.x * blockDim.x) {
        int nn = t >> 6;
        int f  = t & 63;
        float v = (acc[t] + hs[t]) * dinv[nn] + b[f];
        acc[t] = v > 0.f ? v : NEG_SLOPE_C * v;
    }
}

// ---------------- final FC: out[n,c] = sum_k h[n,k] Wfc[k,c] + bfc[c] ----------------
__global__ __launch_bounds__(256) void k_fc(const float* __restrict__ h,
                                            const float* __restrict__ W,
                                            const float* __restrict__ b,
                                            float* __restrict__ out, int n) {
    __shared__ float Ws[HID_C * N_CLS_C];
    for (int i = threadIdx.x; i < HID_C * N_CLS_C; i += blockDim.x) Ws[i] = W[i];
    __syncthreads();
    int total = n * N_CLS_C;
    for (int t = blockIdx.x * blockDim.x + threadIdx.x; t < total; t += gridDim.x * blockDim.x) {
        int nn = t / N_CLS_C;
        int c  = t - nn * N_CLS_C;
        const float* row = h + (long long)nn * HID_C;
        float s = b[c];
#pragma unroll
        for (int k = 0; k < HID_C; ++k) s += row[k] * Ws[k * N_CLS_C + c];
        out[t] = s;
    }
}

extern "C" void kernel_launch(void* const* d_in, const int* in_sizes, int n_in,
                              void* d_out, int out_size, void* d_ws, size_t ws_size,
                              hipStream_t stream) {
    const float* x   = (const float*)d_in[0];
    const int*   ei  = (const int*)d_in[1];   // int32 (JAX default x64-disabled downcasts int64)
    const float* W1  = (const float*)d_in[2];
    const float* b1  = (const float*)d_in[3];
    const float* W2  = (const float*)d_in[4];
    const float* b2  = (const float*)d_in[5];
    const float* W3  = (const float*)d_in[6];
    const float* b3  = (const float*)d_in[7];
    const float* Wfc = (const float*)d_in[8];
    const float* bfc = (const float*)d_in[9];
    float* out = (float*)d_out;

    const int N = N_NODES_C;
    const int E = N_EDGES_C;
    const int* src = ei;
    const int* dst = ei + E;

    // workspace carve-up
    float* dinv = (float*)d_ws;
    float* buf0 = dinv + N;                   // hs scratch
    float* buf1 = buf0 + (size_t)N * HID_C;   // acc / activation
    float* buf2 = buf1 + (size_t)N * HID_C;   // acc / activation (ping-pong)

    const size_t featBytes = (size_t)N * HID_C * sizeof(float);

    int gN   = (N + 255) / 256;
    int gNF  = (N * HID_C + 255) / 256;       // 25000 blocks
    int gSC  = 4096;                          // scatter: grid-stride, 16384 waves
    int gE   = 2048;                          // deg scatter
    int gFC  = (N * N_CLS_C + 255) / 256;

    // dinv = rsqrt(1 + indeg)
    k_deg_init<<<gN, 256, 0, stream>>>(dinv, N);
    k_deg_scatter<<<gE, 256, 0, stream>>>(dst, dinv, E);
    k_deg_fin<<<gN, 256, 0, stream>>>(dinv, N);

    // ---- layer 1: x(10) -> buf1(64) ----
    k_mm_scale<IN_F_C><<<gNF, 256, 0, stream>>>(x, W1, dinv, buf0, N);
    hipMemsetAsync(buf1, 0, featBytes, stream);
    k_scatter<<<gSC, 256, 0, stream>>>(src, dst, buf0, buf1, E);
    k_act<<<gNF, 256, 0, stream>>>(buf1, buf0, dinv, b1, N);

    // ---- layer 2: buf1 -> buf2 ----
    k_mm_scale<HID_C><<<gNF, 256, 0, stream>>>(buf1, W2, dinv, buf0, N);
    hipMemsetAsync(buf2, 0, featBytes, stream);
    k_scatter<<<gSC, 256, 0, stream>>>(src, dst, buf0, buf2, E);
    k_act<<<gNF, 256, 0, stream>>>(buf2, buf0, dinv, b2, N);

    // ---- layer 3: buf2 -> buf1 ----
    k_mm_scale<HID_C><<<gNF, 256, 0, stream>>>(buf2, W3, dinv, buf0, N);
    hipMemsetAsync(buf1, 0, featBytes, stream);
    k_scatter<<<gSC, 256, 0, stream>>>(src, dst, buf0, buf1, E);
    k_act<<<gNF, 256, 0, stream>>>(buf1, buf0, dinv, b3, N);

    // ---- final FC: buf1 -> out ----
    k_fc<<<gFC, 256, 0, stream>>>(buf1, Wfc, bfc, out, N);
}

// Round 2
// 1329.787 us; speedup vs baseline: 1.7856x; 1.7856x over previous
//
#include <hip/hip_runtime.h>

#define N_NODES_C 100000
#define N_EDGES_C 3200000
#define IN_F_C 10
#define HID_C 64
#define N_CLS_C 10
#define NEG_SLOPE_C 0.01f

// ---------------- CSR build: histogram of dst ----------------
__global__ __launch_bounds__(256) void k_hist(const int* __restrict__ dst, int* __restrict__ cnt, int E) {
    for (int e = blockIdx.x * blockDim.x + threadIdx.x; e < E; e += gridDim.x * blockDim.x)
        atomicAdd(&cnt[dst[e]], 1);
}

// single-block scan: row_ptr (exclusive), cursor copy, dinv = rsqrt(cnt+1)
__global__ __launch_bounds__(1024) void k_scan(const int* __restrict__ cnt,
                                               int* __restrict__ row_ptr,
                                               int* __restrict__ cur,
                                               float* __restrict__ dinv, int n, int E) {
    __shared__ int s[1024];
    const int t = threadIdx.x;
    const int chunk = (n + 1023) / 1024;          // 98
    const int lo = t * chunk;
    const int hi = min(n, lo + chunk);
    int mysum = 0;
    for (int i = lo; i < hi; ++i) mysum += cnt[i];
    s[t] = mysum;
    __syncthreads();
    // Hillis-Steele inclusive scan over 1024
    for (int off = 1; off < 1024; off <<= 1) {
        int v = (t >= off) ? s[t - off] : 0;
        __syncthreads();
        s[t] += v;
        __syncthreads();
    }
    int running = s[t] - mysum;                   // exclusive prefix
    for (int i = lo; i < hi; ++i) {
        int c = cnt[i];
        row_ptr[i] = running;
        cur[i] = running;
        dinv[i] = rsqrtf((float)(c + 1));
        running += c;
    }
    if (t == 0) row_ptr[n] = E;
}

__global__ __launch_bounds__(256) void k_place(const int* __restrict__ src,
                                               const int* __restrict__ dst,
                                               int* __restrict__ cur,
                                               int* __restrict__ col, int E) {
    for (int e = blockIdx.x * blockDim.x + threadIdx.x; e < E; e += gridDim.x * blockDim.x) {
        int d = dst[e];
        int idx = atomicAdd(&cur[d], 1);
        col[idx] = src[e];
    }
}

// ---------------- matmul + dinv scale: hs[n,f] = (sum_k hin[n,k] W[k,f]) * dinv[n] ----------------
template <int K>
__global__ __launch_bounds__(256) void k_mm_scale(const float* __restrict__ hin,
                                                  const float* __restrict__ W,
                                                  const float* __restrict__ dinv,
                                                  float* __restrict__ hs, int n) {
    __shared__ float Ws[K * HID_C];
    for (int i = threadIdx.x; i < K * HID_C; i += blockDim.x) Ws[i] = W[i];
    __syncthreads();
    int total = n * HID_C;
    for (int t = blockIdx.x * blockDim.x + threadIdx.x; t < total; t += gridDim.x * blockDim.x) {
        int nn = t >> 6;          // HID_C == 64
        int f  = t & 63;
        const float* row = hin + (long long)nn * K;
        float s = 0.f;
#pragma unroll
        for (int k = 0; k < K; ++k) s += row[k] * Ws[k * HID_C + f];
        hs[t] = s * dinv[nn];
    }
}

// ---------------- fused gather + epilogue: one wave per node ----------------
// out[d,lane] = lrelu( (hs[d,lane] + sum_e hs[col[e],lane]) * dinv[d] + b[lane] )
__global__ __launch_bounds__(256) void k_gather(const int* __restrict__ row_ptr,
                                                const int* __restrict__ col,
                                                const float* __restrict__ hs,
                                                const float* __restrict__ dinv,
                                                const float* __restrict__ b,
                                                float* __restrict__ out, int n) {
    const int lane = threadIdx.x & 63;
    const int d = (blockIdx.x << 2) + (threadIdx.x >> 6);   // 4 waves / block
    if (d >= n) return;
    const int beg = row_ptr[d];
    const int end = row_ptr[d + 1];
    float acc = hs[(d << 6) + lane];                        // self loop
    int e = beg;
    for (; e + 3 < end; e += 4) {
        int s0 = col[e], s1 = col[e + 1], s2 = col[e + 2], s3 = col[e + 3];
        float v0 = hs[(s0 << 6) + lane];
        float v1 = hs[(s1 << 6) + lane];
        float v2 = hs[(s2 << 6) + lane];
        float v3 = hs[(s3 << 6) + lane];
        acc += v0; acc += v1; acc += v2; acc += v3;
    }
    for (; e < end; ++e) acc += hs[(col[e] << 6) + lane];
    float v = acc * dinv[d] + b[lane];
    out[(d << 6) + lane] = v > 0.f ? v : NEG_SLOPE_C * v;
}

// ---------------- final FC ----------------
__global__ __launch_bounds__(256) void k_fc(const float* __restrict__ h,
                                            const float* __restrict__ W,
                                            const float* __restrict__ b,
                                            float* __restrict__ out, int n) {
    __shared__ float Ws[HID_C * N_CLS_C];
    for (int i = threadIdx.x; i < HID_C * N_CLS_C; i += blockDim.x) Ws[i] = W[i];
    __syncthreads();
    int total = n * N_CLS_C;
    for (int t = blockIdx.x * blockDim.x + threadIdx.x; t < total; t += gridDim.x * blockDim.x) {
        int nn = t / N_CLS_C;
        int c  = t - nn * N_CLS_C;
        const float* row = h + (long long)nn * HID_C;
        float s = b[c];
#pragma unroll
        for (int k = 0; k < HID_C; ++k) s += row[k] * Ws[k * N_CLS_C + c];
        out[t] = s;
    }
}

extern "C" void kernel_launch(void* const* d_in, const int* in_sizes, int n_in,
                              void* d_out, int out_size, void* d_ws, size_t ws_size,
                              hipStream_t stream) {
    const float* x   = (const float*)d_in[0];
    const int*   ei  = (const int*)d_in[1];   // int32
    const float* W1  = (const float*)d_in[2];
    const float* b1  = (const float*)d_in[3];
    const float* W2  = (const float*)d_in[4];
    const float* b2  = (const float*)d_in[5];
    const float* W3  = (const float*)d_in[6];
    const float* b3  = (const float*)d_in[7];
    const float* Wfc = (const float*)d_in[8];
    const float* bfc = (const float*)d_in[9];
    float* out = (float*)d_out;

    const int N = N_NODES_C;
    const int E = N_EDGES_C;
    const int* src = ei;
    const int* dst = ei + E;

    // workspace carve-up
    float* dinv    = (float*)d_ws;                    // N
    int*   cnt     = (int*)(dinv + N);                // N (also cursor)
    int*   row_ptr = cnt + N;                         // N+1
    int*   col     = row_ptr + (N + 1);               // E
    float* hs      = (float*)(col + E);               // N*64
    float* act     = hs + (size_t)N * HID_C;          // N*64

    int gN4  = (N + 3) / 4;                           // gather: 4 waves/block
    int gNF  = (N * HID_C + 255) / 256;
    int gE   = 2048;
    int gFC  = (N * N_CLS_C + 255) / 256;

    // ---- CSR build (+ dinv) ----
    hipMemsetAsync(cnt, 0, (size_t)N * sizeof(int), stream);
    k_hist<<<gE, 256, 0, stream>>>(dst, cnt, E);
    k_scan<<<1, 1024, 0, stream>>>(cnt, row_ptr, cnt /*cursor reuse*/, dinv, N, E);
    k_place<<<gE, 256, 0, stream>>>(src, dst, cnt, col, E);

    // ---- layer 1: x(10) -> act ----
    k_mm_scale<IN_F_C><<<gNF, 256, 0, stream>>>(x, W1, dinv, hs, N);
    k_gather<<<gN4, 256, 0, stream>>>(row_ptr, col, hs, dinv, b1, act, N);

    // ---- layer 2: act -> act ----
    k_mm_scale<HID_C><<<gNF, 256, 0, stream>>>(act, W2, dinv, hs, N);
    k_gather<<<gN4, 256, 0, stream>>>(row_ptr, col, hs, dinv, b2, act, N);

    // ---- layer 3: act -> act ----
    k_mm_scale<HID_C><<<gNF, 256, 0, stream>>>(act, W3, dinv, hs, N);
    k_gather<<<gN4, 256, 0, stream>>>(row_ptr, col, hs, dinv, b3, act, N);

    // ---- final FC ----
    k_fc<<<gFC, 256, 0, stream>>>(act, Wfc, bfc, out, N);
}

// Round 3
// 1067.387 us; speedup vs baseline: 2.2246x; 1.2458x over previous
//
#include <hip/hip_runtime.h>

#define N_NODES_C 100000
#define N_EDGES_C 3200000
#define IN_F_C 10
#define HID_C 64
#define N_CLS_C 10
#define NEG_SLOPE_C 0.01f

// ---------------- CSR build: histogram of dst ----------------
__global__ __launch_bounds__(256) void k_hist(const int* __restrict__ dst, int* __restrict__ cnt, int E) {
    for (int e = blockIdx.x * blockDim.x + threadIdx.x; e < E; e += gridDim.x * blockDim.x)
        atomicAdd(&cnt[dst[e]], 1);
}

// ---------------- parallel scan, 3 kernels, 1024 elements/block ----------------
__global__ __launch_bounds__(256) void k_scanA(const int* __restrict__ cnt, int* __restrict__ blkSum, int n) {
    __shared__ int red[4];
    int base = blockIdx.x * 1024 + threadIdx.x * 4;
    int s = 0;
    if (base + 3 < n) { int4 v = *(const int4*)(cnt + base); s = v.x + v.y + v.z + v.w; }
    else { for (int i = 0; i < 4; ++i) if (base + i < n) s += cnt[base + i]; }
    for (int off = 32; off; off >>= 1) s += __shfl_down(s, off, 64);
    if ((threadIdx.x & 63) == 0) red[threadIdx.x >> 6] = s;
    __syncthreads();
    if (threadIdx.x == 0) blkSum[blockIdx.x] = red[0] + red[1] + red[2] + red[3];
}

__global__ __launch_bounds__(128) void k_scanB(const int* __restrict__ blkSum, int* __restrict__ blkOff, int nb) {
    __shared__ int s[128];
    int t = threadIdx.x;
    int v = (t < nb) ? blkSum[t] : 0;
    s[t] = v;
    __syncthreads();
    for (int off = 1; off < 128; off <<= 1) {
        int u = (t >= off) ? s[t - off] : 0;
        __syncthreads();
        s[t] += u;
        __syncthreads();
    }
    if (t < nb) blkOff[t] = s[t] - v;   // exclusive prefix
}

__global__ __launch_bounds__(256) void k_scanC(const int* __restrict__ cnt, const int* __restrict__ blkOff,
                                               int* __restrict__ row_ptr, int* __restrict__ cur,
                                               float* __restrict__ dinv, int n, int E) {
    __shared__ int sm[256];
    int t = threadIdx.x;
    int base = blockIdx.x * 1024 + t * 4;
    int c0 = 0, c1 = 0, c2 = 0, c3 = 0;
    if (base + 3 < n) { int4 v = *(const int4*)(cnt + base); c0 = v.x; c1 = v.y; c2 = v.z; c3 = v.w; }
    else {
        if (base     < n) c0 = cnt[base];
        if (base + 1 < n) c1 = cnt[base + 1];
        if (base + 2 < n) c2 = cnt[base + 2];
        if (base + 3 < n) c3 = cnt[base + 3];
    }
    int tsum = c0 + c1 + c2 + c3;
    sm[t] = tsum;
    __syncthreads();
    for (int off = 1; off < 256; off <<= 1) {
        int u = (t >= off) ? sm[t - off] : 0;
        __syncthreads();
        sm[t] += u;
        __syncthreads();
    }
    int pre = blkOff[blockIdx.x] + sm[t] - tsum;   // exclusive prefix for this thread's 4
    int p0 = pre, p1 = pre + c0, p2 = p1 + c1, p3 = p2 + c2;
    if (base + 3 < n) {
        *(int4*)(row_ptr + base) = make_int4(p0, p1, p2, p3);
        *(int4*)(cur + base)     = make_int4(p0, p1, p2, p3);
        *(float4*)(dinv + base)  = make_float4(rsqrtf(c0 + 1.f), rsqrtf(c1 + 1.f),
                                               rsqrtf(c2 + 1.f), rsqrtf(c3 + 1.f));
    } else {
        int pp[4] = {p0, p1, p2, p3};
        int cc[4] = {c0, c1, c2, c3};
        for (int i = 0; i < 4; ++i) if (base + i < n) {
            row_ptr[base + i] = pp[i];
            cur[base + i] = pp[i];
            dinv[base + i] = rsqrtf(cc[i] + 1.f);
        }
    }
    if (blockIdx.x == 0 && t == 0) row_ptr[n] = E;
}

__global__ __launch_bounds__(256) void k_place(const int* __restrict__ src,
                                               const int* __restrict__ dst,
                                               int* __restrict__ cur,
                                               int* __restrict__ col, int E) {
    for (int e = blockIdx.x * blockDim.x + threadIdx.x; e < E; e += gridDim.x * blockDim.x) {
        int d = dst[e];
        int idx = atomicAdd(&cur[d], 1);
        col[idx] = src[e];
    }
}

// ---------------- matmul + dinv scale ----------------
template <int K>
__global__ __launch_bounds__(256) void k_mm_scale(const float* __restrict__ hin,
                                                  const float* __restrict__ W,
                                                  const float* __restrict__ dinv,
                                                  float* __restrict__ hs, int n) {
    __shared__ float Ws[K * HID_C];
    for (int i = threadIdx.x; i < K * HID_C; i += blockDim.x) Ws[i] = W[i];
    __syncthreads();
    int total = n * HID_C;
    for (int t = blockIdx.x * blockDim.x + threadIdx.x; t < total; t += gridDim.x * blockDim.x) {
        int nn = t >> 6;
        int f  = t & 63;
        const float* row = hin + (long long)nn * K;
        float s = 0.f;
#pragma unroll
        for (int k = 0; k < K; ++k) s += row[k] * Ws[k * HID_C + f];
        hs[t] = s * dinv[nn];
    }
}

// ---------------- fused gather + epilogue ----------------
__global__ __launch_bounds__(256) void k_gather(const int* __restrict__ row_ptr,
                                                const int* __restrict__ col,
                                                const float* __restrict__ hs,
                                                const float* __restrict__ dinv,
                                                const float* __restrict__ b,
                                                float* __restrict__ out, int n) {
    const int lane = threadIdx.x & 63;
    const int d = (blockIdx.x << 2) + (threadIdx.x >> 6);   // 4 waves / block
    if (d >= n) return;
    const int beg = row_ptr[d];
    const int end = row_ptr[d + 1];
    float acc = hs[(d << 6) + lane];                        // self loop
    int e = beg;
    for (; e + 3 < end; e += 4) {
        int s0 = col[e], s1 = col[e + 1], s2 = col[e + 2], s3 = col[e + 3];
        acc += hs[(s0 << 6) + lane];
        acc += hs[(s1 << 6) + lane];
        acc += hs[(s2 << 6) + lane];
        acc += hs[(s3 << 6) + lane];
    }
    for (; e < end; ++e) acc += hs[(col[e] << 6) + lane];
    float v = acc * dinv[d] + b[lane];
    out[(d << 6) + lane] = v > 0.f ? v : NEG_SLOPE_C * v;
}

// ---------------- final FC ----------------
__global__ __launch_bounds__(256) void k_fc(const float* __restrict__ h,
                                            const float* __restrict__ W,
                                            const float* __restrict__ b,
                                            float* __restrict__ out, int n) {
    __shared__ float Ws[HID_C * N_CLS_C];
    for (int i = threadIdx.x; i < HID_C * N_CLS_C; i += blockDim.x) Ws[i] = W[i];
    __syncthreads();
    int total = n * N_CLS_C;
    for (int t = blockIdx.x * blockDim.x + threadIdx.x; t < total; t += gridDim.x * blockDim.x) {
        int nn = t / N_CLS_C;
        int c  = t - nn * N_CLS_C;
        const float* row = h + (long long)nn * HID_C;
        float s = b[c];
#pragma unroll
        for (int k = 0; k < HID_C; ++k) s += row[k] * Ws[k * N_CLS_C + c];
        out[t] = s;
    }
}

extern "C" void kernel_launch(void* const* d_in, const int* in_sizes, int n_in,
                              void* d_out, int out_size, void* d_ws, size_t ws_size,
                              hipStream_t stream) {
    const float* x   = (const float*)d_in[0];
    const int*   ei  = (const int*)d_in[1];
    const float* W1  = (const float*)d_in[2];
    const float* b1  = (const float*)d_in[3];
    const float* W2  = (const float*)d_in[4];
    const float* b2  = (const float*)d_in[5];
    const float* W3  = (const float*)d_in[6];
    const float* b3  = (const float*)d_in[7];
    const float* Wfc = (const float*)d_in[8];
    const float* bfc = (const float*)d_in[9];
    float* out = (float*)d_out;

    const int N = N_NODES_C;
    const int E = N_EDGES_C;
    const int* src = ei;
    const int* dst = ei + E;

    const int NB = (N + 1023) / 1024;                 // 98 scan blocks

    // workspace carve-up (all 16B-aligned)
    float* dinv    = (float*)d_ws;                    // N
    int*   cnt     = (int*)(dinv + N);                // N
    int*   row_ptr = cnt + N;                         // N+4 (padded)
    int*   cur     = row_ptr + N + 4;                 // N
    int*   blkSum  = cur + N;                         // NB (pad 128)
    int*   blkOff  = blkSum + 128;                    // NB (pad 128)
    int*   col     = blkOff + 128;                    // E
    float* hs      = (float*)(col + E);               // N*64
    float* act     = hs + (size_t)N * HID_C;          // N*64

    int gN4  = (N + 3) / 4;
    int gNF  = (N * HID_C + 255) / 256;
    int gE   = 2048;
    int gFC  = (N * N_CLS_C + 255) / 256;

    // ---- CSR build (+ dinv) ----
    hipMemsetAsync(cnt, 0, (size_t)N * sizeof(int), stream);
    k_hist<<<gE, 256, 0, stream>>>(dst, cnt, E);
    k_scanA<<<NB, 256, 0, stream>>>(cnt, blkSum, N);
    k_scanB<<<1, 128, 0, stream>>>(blkSum, blkOff, NB);
    k_scanC<<<NB, 256, 0, stream>>>(cnt, blkOff, row_ptr, cur, dinv, N, E);
    k_place<<<gE, 256, 0, stream>>>(src, dst, cur, col, E);

    // ---- layer 1: x(10) -> act ----
    k_mm_scale<IN_F_C><<<gNF, 256, 0, stream>>>(x, W1, dinv, hs, N);
    k_gather<<<gN4, 256, 0, stream>>>(row_ptr, col, hs, dinv, b1, act, N);

    // ---- layer 2 ----
    k_mm_scale<HID_C><<<gNF, 256, 0, stream>>>(act, W2, dinv, hs, N);
    k_gather<<<gN4, 256, 0, stream>>>(row_ptr, col, hs, dinv, b2, act, N);

    // ---- layer 3 ----
    k_mm_scale<HID_C><<<gNF, 256, 0, stream>>>(act, W3, dinv, hs, N);
    k_gather<<<gN4, 256, 0, stream>>>(row_ptr, col, hs, dinv, b3, act, N);

    // ---- final FC ----
    k_fc<<<gFC, 256, 0, stream>>>(act, Wfc, bfc, out, N);
}

// Round 4
// 935.044 us; speedup vs baseline: 2.5394x; 1.1415x over previous
//
#include <hip/hip_runtime.h>

#define N_NODES_C 100000
#define N_EDGES_C 3200000
#define IN_F_C 10
#define HID_C 64
#define N_CLS_C 10
#define NEG_SLOPE_C 0.01f

#define NBUCK 98        // ceil(100000 / 1024), bucket = dst >> 10
#define BCAP  36864     // mean 32768, sigma ~180 -> +22 sigma headroom
#define TILE  4096      // edges per block in k_bucket (256 thr x 16)

// ---------------- pass 1: bucket partition + fused per-node histogram ----------------
__global__ __launch_bounds__(256) void k_bucket(const int* __restrict__ src,
                                                const int* __restrict__ dst,
                                                int* __restrict__ cnt,
                                                int* __restrict__ bcur,
                                                int2* __restrict__ pairs, int E) {
    __shared__ int lcnt[NBUCK];
    __shared__ int gbase[NBUCK];
    const int t = threadIdx.x;
    for (int i = t; i < NBUCK; i += 256) lcnt[i] = 0;
    __syncthreads();
    const int base = blockIdx.x * TILE;
    int s[16], d[16], r[16], nb[16];
#pragma unroll
    for (int i = 0; i < 16; ++i) {
        int e = base + t + i * 256;          // coalesced within tile
        if (e < E) {
            s[i] = src[e];
            d[i] = dst[e];
            int b = d[i] >> 10;
            nb[i] = b;
            r[i] = atomicAdd(&lcnt[b], 1);   // tile-local rank
            atomicAdd(&cnt[d[i]], 1);        // fused degree histogram
        }
    }
    __syncthreads();
    for (int i = t; i < NBUCK; i += 256)
        gbase[i] = lcnt[i] ? atomicAdd(&bcur[i], lcnt[i]) : 0;
    __syncthreads();
#pragma unroll
    for (int i = 0; i < 16; ++i) {
        int e = base + t + i * 256;
        if (e < E) {
            int pos = gbase[nb[i]] + r[i];
            if (pos < BCAP) pairs[(size_t)nb[i] * BCAP + pos] = make_int2(s[i], d[i]);
        }
    }
}

// ---------------- parallel scan, 3 kernels, 1024 elements/block ----------------
__global__ __launch_bounds__(256) void k_scanA(const int* __restrict__ cnt, int* __restrict__ blkSum, int n) {
    __shared__ int red[4];
    int base = blockIdx.x * 1024 + threadIdx.x * 4;
    int s = 0;
    if (base + 3 < n) { int4 v = *(const int4*)(cnt + base); s = v.x + v.y + v.z + v.w; }
    else { for (int i = 0; i < 4; ++i) if (base + i < n) s += cnt[base + i]; }
    for (int off = 32; off; off >>= 1) s += __shfl_down(s, off, 64);
    if ((threadIdx.x & 63) == 0) red[threadIdx.x >> 6] = s;
    __syncthreads();
    if (threadIdx.x == 0) blkSum[blockIdx.x] = red[0] + red[1] + red[2] + red[3];
}

__global__ __launch_bounds__(128) void k_scanB(const int* __restrict__ blkSum, int* __restrict__ blkOff, int nb) {
    __shared__ int s[128];
    int t = threadIdx.x;
    int v = (t < nb) ? blkSum[t] : 0;
    s[t] = v;
    __syncthreads();
    for (int off = 1; off < 128; off <<= 1) {
        int u = (t >= off) ? s[t - off] : 0;
        __syncthreads();
        s[t] += u;
        __syncthreads();
    }
    if (t < nb) blkOff[t] = s[t] - v;   // exclusive prefix
}

__global__ __launch_bounds__(256) void k_scanC(const int* __restrict__ cnt, const int* __restrict__ blkOff,
                                               int* __restrict__ row_ptr, int* __restrict__ cur,
                                               float* __restrict__ dinv, int n, int E) {
    __shared__ int sm[256];
    int t = threadIdx.x;
    int base = blockIdx.x * 1024 + t * 4;
    int c0 = 0, c1 = 0, c2 = 0, c3 = 0;
    if (base + 3 < n) { int4 v = *(const int4*)(cnt + base); c0 = v.x; c1 = v.y; c2 = v.z; c3 = v.w; }
    else {
        if (base     < n) c0 = cnt[base];
        if (base + 1 < n) c1 = cnt[base + 1];
        if (base + 2 < n) c2 = cnt[base + 2];
        if (base + 3 < n) c3 = cnt[base + 3];
    }
    int tsum = c0 + c1 + c2 + c3;
    sm[t] = tsum;
    __syncthreads();
    for (int off = 1; off < 256; off <<= 1) {
        int u = (t >= off) ? sm[t - off] : 0;
        __syncthreads();
        sm[t] += u;
        __syncthreads();
    }
    int pre = blkOff[blockIdx.x] + sm[t] - tsum;
    int p0 = pre, p1 = pre + c0, p2 = p1 + c1, p3 = p2 + c2;
    if (base + 3 < n) {
        *(int4*)(row_ptr + base) = make_int4(p0, p1, p2, p3);
        *(int4*)(cur + base)     = make_int4(p0, p1, p2, p3);
        *(float4*)(dinv + base)  = make_float4(rsqrtf(c0 + 1.f), rsqrtf(c1 + 1.f),
                                               rsqrtf(c2 + 1.f), rsqrtf(c3 + 1.f));
    } else {
        int pp[4] = {p0, p1, p2, p3};
        int cc[4] = {c0, c1, c2, c3};
        for (int i = 0; i < 4; ++i) if (base + i < n) {
            row_ptr[base + i] = pp[i];
            cur[base + i] = pp[i];
            dinv[base + i] = rsqrtf(cc[i] + 1.f);
        }
    }
    if (blockIdx.x == 0 && t == 0) row_ptr[n] = E;
}

// ---------------- pass 2: per-bucket CSR placement (localized writes) ----------------
__global__ __launch_bounds__(1024) void k_place2(const int2* __restrict__ pairs,
                                                 const int* __restrict__ bcur,
                                                 int* __restrict__ cur,
                                                 int* __restrict__ col) {
    const int b = blockIdx.x;
    const int n = min(bcur[b], BCAP);
    const int2* p = pairs + (size_t)b * BCAP;
    for (int i = threadIdx.x; i < n; i += 1024) {
        int2 e = p[i];
        int idx = atomicAdd(&cur[e.y], 1);   // 4 KB window -> L1/L2 resident
        col[idx] = e.x;                      // ~131 KB window, single CU
    }
}

// ---------------- matmul + dinv scale ----------------
template <int K>
__global__ __launch_bounds__(256) void k_mm_scale(const float* __restrict__ hin,
                                                  const float* __restrict__ W,
                                                  const float* __restrict__ dinv,
                                                  float* __restrict__ hs, int n) {
    __shared__ float Ws[K * HID_C];
    for (int i = threadIdx.x; i < K * HID_C; i += blockDim.x) Ws[i] = W[i];
    __syncthreads();
    int total = n * HID_C;
    for (int t = blockIdx.x * blockDim.x + threadIdx.x; t < total; t += gridDim.x * blockDim.x) {
        int nn = t >> 6;
        int f  = t & 63;
        const float* row = hin + (long long)nn * K;
        float s = 0.f;
#pragma unroll
        for (int k = 0; k < K; ++k) s += row[k] * Ws[k * HID_C + f];
        hs[t] = s * dinv[nn];
    }
}

// ---------------- fused gather + epilogue ----------------
__global__ __launch_bounds__(256) void k_gather(const int* __restrict__ row_ptr,
                                                const int* __restrict__ col,
                                                const float* __restrict__ hs,
                                                const float* __restrict__ dinv,
                                                const float* __restrict__ b,
                                                float* __restrict__ out, int n) {
    const int lane = threadIdx.x & 63;
    const int d = (blockIdx.x << 2) + (threadIdx.x >> 6);   // 4 waves / block
    if (d >= n) return;
    const int beg = row_ptr[d];
    const int end = row_ptr[d + 1];
    float acc = hs[(d << 6) + lane];                        // self loop
    int e = beg;
    for (; e + 3 < end; e += 4) {
        int s0 = col[e], s1 = col[e + 1], s2 = col[e + 2], s3 = col[e + 3];
        acc += hs[(s0 << 6) + lane];
        acc += hs[(s1 << 6) + lane];
        acc += hs[(s2 << 6) + lane];
        acc += hs[(s3 << 6) + lane];
    }
    for (; e < end; ++e) acc += hs[(col[e] << 6) + lane];
    float v = acc * dinv[d] + b[lane];
    out[(d << 6) + lane] = v > 0.f ? v : NEG_SLOPE_C * v;
}

// ---------------- final FC ----------------
__global__ __launch_bounds__(256) void k_fc(const float* __restrict__ h,
                                            const float* __restrict__ W,
                                            const float* __restrict__ b,
                                            float* __restrict__ out, int n) {
    __shared__ float Ws[HID_C * N_CLS_C];
    for (int i = threadIdx.x; i < HID_C * N_CLS_C; i += blockDim.x) Ws[i] = W[i];
    __syncthreads();
    int total = n * N_CLS_C;
    for (int t = blockIdx.x * blockDim.x + threadIdx.x; t < total; t += gridDim.x * blockDim.x) {
        int nn = t / N_CLS_C;
        int c  = t - nn * N_CLS_C;
        const float* row = h + (long long)nn * HID_C;
        float s = b[c];
#pragma unroll
        for (int k = 0; k < HID_C; ++k) s += row[k] * Ws[k * N_CLS_C + c];
        out[t] = s;
    }
}

extern "C" void kernel_launch(void* const* d_in, const int* in_sizes, int n_in,
                              void* d_out, int out_size, void* d_ws, size_t ws_size,
                              hipStream_t stream) {
    const float* x   = (const float*)d_in[0];
    const int*   ei  = (const int*)d_in[1];
    const float* W1  = (const float*)d_in[2];
    const float* b1  = (const float*)d_in[3];
    const float* W2  = (const float*)d_in[4];
    const float* b2  = (const float*)d_in[5];
    const float* W3  = (const float*)d_in[6];
    const float* b3  = (const float*)d_in[7];
    const float* Wfc = (const float*)d_in[8];
    const float* bfc = (const float*)d_in[9];
    float* out = (float*)d_out;

    const int N = N_NODES_C;
    const int E = N_EDGES_C;
    const int* src = ei;
    const int* dst = ei + E;

    const int NB = (N + 1023) / 1024;                 // 98 scan blocks

    // workspace carve-up (all 16B-aligned)
    float* dinv    = (float*)d_ws;                    // N
    int*   cnt     = (int*)(dinv + N);                // N      (zeroed)
    int*   bcur    = cnt + N;                         // 128    (zeroed, same memset)
    int*   row_ptr = bcur + 128;                      // N+4
    int*   cur     = row_ptr + N + 4;                 // N
    int*   blkSum  = cur + N;                         // 128
    int*   blkOff  = blkSum + 128;                    // 128
    int*   col     = blkOff + 128;                    // E
    float* hs      = (float*)(col + E);               // N*64
    float* act     = hs + (size_t)N * HID_C;          // N*64
    int2*  pairs   = (int2*)hs;                       // 98*BCAP int2 = 28.9 MB, dead before hs written

    int gN4  = (N + 3) / 4;
    int gNF  = (N * HID_C + 255) / 256;
    int gBK  = (E + TILE - 1) / TILE;                 // 782
    int gFC  = (N * N_CLS_C + 255) / 256;

    // ---- CSR build (+ dinv) ----
    hipMemsetAsync(cnt, 0, (size_t)(N + 128) * sizeof(int), stream);   // cnt + bcur
    k_bucket<<<gBK, 256, 0, stream>>>(src, dst, cnt, bcur, pairs, E);
    k_scanA<<<NB, 256, 0, stream>>>(cnt, blkSum, N);
    k_scanB<<<1, 128, 0, stream>>>(blkSum, blkOff, NB);
    k_scanC<<<NB, 256, 0, stream>>>(cnt, blkOff, row_ptr, cur, dinv, N, E);
    k_place2<<<NBUCK, 1024, 0, stream>>>(pairs, bcur, cur, col);

    // ---- layer 1: x(10) -> act ----
    k_mm_scale<IN_F_C><<<gNF, 256, 0, stream>>>(x, W1, dinv, hs, N);
    k_gather<<<gN4, 256, 0, stream>>>(row_ptr, col, hs, dinv, b1, act, N);

    // ---- layer 2 ----
    k_mm_scale<HID_C><<<gNF, 256, 0, stream>>>(act, W2, dinv, hs, N);
    k_gather<<<gN4, 256, 0, stream>>>(row_ptr, col, hs, dinv, b2, act, N);

    // ---- layer 3 ----
    k_mm_scale<HID_C><<<gNF, 256, 0, stream>>>(act, W3, dinv, hs, N);
    k_gather<<<gN4, 256, 0, stream>>>(row_ptr, col, hs, dinv, b3, act, N);

    // ---- final FC ----
    k_fc<<<gFC, 256, 0, stream>>>(act, Wfc, bfc, out, N);
}

// Round 5
// 760.292 us; speedup vs baseline: 3.1231x; 1.2298x over previous
//
#include <hip/hip_runtime.h>

#define N_NODES_C 100000
#define N_EDGES_C 3200000
#define IN_F_C 10
#define HID_C 64
#define N_CLS_C 10
#define NEG_SLOPE_C 0.01f

#define NBUCK 98        // ceil(100000/1024); bucket = dst >> 10
#define BCAP  36864     // mean 32768, sigma ~180 -> +22 sigma headroom
#define TILE  2048      // edges per block in k_bucket (256 thr x 8)

// ---------------- pass 1: bucket partition, packed pairs, no global atomics per edge ----------------
__global__ __launch_bounds__(256) void k_bucket(const int* __restrict__ src,
                                                const int* __restrict__ dst,
                                                int* __restrict__ bcur,
                                                int* __restrict__ pairs, int E) {
    __shared__ int lcnt[NBUCK];
    __shared__ int gbase[NBUCK];
    const int t = threadIdx.x;
    for (int i = t; i < NBUCK; i += 256) lcnt[i] = 0;
    __syncthreads();
    const int base = blockIdx.x * TILE;
    int p[8], r[8], nb[8];
#pragma unroll
    for (int i = 0; i < 8; ++i) {
        int e = base + t + i * 256;          // coalesced within tile
        if (e < E) {
            int s = src[e], d = dst[e];
            int b = d >> 10;
            nb[i] = b;
            p[i] = (s << 10) | (d & 1023);   // src<2^17, local dst<2^10
            r[i] = atomicAdd(&lcnt[b], 1);   // tile-local rank (LDS)
        }
    }
    __syncthreads();
    for (int i = t; i < NBUCK; i += 256)
        gbase[i] = lcnt[i] ? atomicAdd(&bcur[i], lcnt[i]) : 0;
    __syncthreads();
#pragma unroll
    for (int i = 0; i < 8; ++i) {
        int e = base + t + i * 256;
        if (e < E) {
            int pos = gbase[nb[i]] + r[i];
            if (pos < BCAP) pairs[nb[i] * BCAP + pos] = p[i];
        }
    }
}

// ---------------- tiny scan of 98 bucket sizes -> bucket base offsets ----------------
__global__ __launch_bounds__(128) void k_bscan(const int* __restrict__ bcur,
                                               int* __restrict__ bOff, int nbk) {
    __shared__ int s[128];
    int t = threadIdx.x;
    int v = (t < nbk) ? bcur[t] : 0;
    s[t] = v;
    __syncthreads();
    for (int off = 1; off < 128; off <<= 1) {
        int u = (t >= off) ? s[t - off] : 0;
        __syncthreads();
        s[t] += u;
        __syncthreads();
    }
    if (t < nbk) bOff[t] = s[t] - v;   // exclusive prefix
}

// ---------------- pass 2: per-bucket hist + scan + row_ptr/dinv + placement, all LDS-local ----------------
__global__ __launch_bounds__(1024) void k_build(const int* __restrict__ pairs,
                                                const int* __restrict__ bcur,
                                                const int* __restrict__ bOff,
                                                int* __restrict__ row_ptr,
                                                float* __restrict__ dinv,
                                                int* __restrict__ col) {
    __shared__ int hist[1024];
    __shared__ int sm[1024];
    const int b = blockIdx.x;
    const int t = threadIdx.x;
    const int n = min(bcur[b], BCAP);
    const int base = bOff[b];
    const int* pp = pairs + b * BCAP;

    hist[t] = 0;
    __syncthreads();
    // phase 1: local histogram (LDS atomics, 1024 counters -> rare collisions)
    for (int i = t; i < n; i += 1024) atomicAdd(&hist[pp[i] & 1023], 1);
    __syncthreads();
    int c = hist[t];
    // phase 2: block-wide scan
    sm[t] = c;
    __syncthreads();
    for (int off = 1; off < 1024; off <<= 1) {
        int u = (t >= off) ? sm[t - off] : 0;
        __syncthreads();
        sm[t] += u;
        __syncthreads();
    }
    int rp = base + sm[t] - c;           // absolute exclusive prefix
    int gnode = (b << 10) + t;
    if (gnode < N_NODES_C) {
        row_ptr[gnode] = rp;
        dinv[gnode] = rsqrtf((float)(c + 1));
        if (gnode == N_NODES_C - 1) row_ptr[N_NODES_C] = rp + c;
    }
    __syncthreads();
    sm[t] = rp;                          // reuse sm as absolute cursor
    __syncthreads();
    // phase 3: placement (LDS cursor atomics; col writes within a ~131KB window)
    for (int i = t; i < n; i += 1024) {
        int p = pp[i];
        int idx = atomicAdd(&sm[p & 1023], 1);
        col[idx] = p >> 10;
    }
}

// ---------------- matmul + dinv scale ----------------
template <int K>
__global__ __launch_bounds__(256) void k_mm_scale(const float* __restrict__ hin,
                                                  const float* __restrict__ W,
                                                  const float* __restrict__ dinv,
                                                  float* __restrict__ hs, int n) {
    __shared__ float Ws[K * HID_C];
    for (int i = threadIdx.x; i < K * HID_C; i += blockDim.x) Ws[i] = W[i];
    __syncthreads();
    int total = n * HID_C;
    for (int t = blockIdx.x * blockDim.x + threadIdx.x; t < total; t += gridDim.x * blockDim.x) {
        int nn = t >> 6;
        int f  = t & 63;
        const float* row = hin + (long long)nn * K;
        float s = 0.f;
#pragma unroll
        for (int k = 0; k < K; ++k) s += row[k] * Ws[k * HID_C + f];
        hs[t] = s * dinv[nn];
    }
}

// ---------------- fused gather + epilogue ----------------
__global__ __launch_bounds__(256) void k_gather(const int* __restrict__ row_ptr,
                                                const int* __restrict__ col,
                                                const float* __restrict__ hs,
                                                const float* __restrict__ dinv,
                                                const float* __restrict__ b,
                                                float* __restrict__ out, int n) {
    const int lane = threadIdx.x & 63;
    const int d = (blockIdx.x << 2) + (threadIdx.x >> 6);   // 4 waves / block
    if (d >= n) return;
    const int beg = row_ptr[d];
    const int end = row_ptr[d + 1];
    float acc = hs[(d << 6) + lane];                        // self loop
    int e = beg;
    for (; e + 3 < end; e += 4) {
        int s0 = col[e], s1 = col[e + 1], s2 = col[e + 2], s3 = col[e + 3];
        acc += hs[(s0 << 6) + lane];
        acc += hs[(s1 << 6) + lane];
        acc += hs[(s2 << 6) + lane];
        acc += hs[(s3 << 6) + lane];
    }
    for (; e < end; ++e) acc += hs[(col[e] << 6) + lane];
    float v = acc * dinv[d] + b[lane];
    out[(d << 6) + lane] = v > 0.f ? v : NEG_SLOPE_C * v;
}

// ---------------- final FC ----------------
__global__ __launch_bounds__(256) void k_fc(const float* __restrict__ h,
                                            const float* __restrict__ W,
                                            const float* __restrict__ b,
                                            float* __restrict__ out, int n) {
    __shared__ float Ws[HID_C * N_CLS_C];
    for (int i = threadIdx.x; i < HID_C * N_CLS_C; i += blockDim.x) Ws[i] = W[i];
    __syncthreads();
    int total = n * N_CLS_C;
    for (int t = blockIdx.x * blockDim.x + threadIdx.x; t < total; t += gridDim.x * blockDim.x) {
        int nn = t / N_CLS_C;
        int c  = t - nn * N_CLS_C;
        const float* row = h + (long long)nn * HID_C;
        float s = b[c];
#pragma unroll
        for (int k = 0; k < HID_C; ++k) s += row[k] * Ws[k * N_CLS_C + c];
        out[t] = s;
    }
}

extern "C" void kernel_launch(void* const* d_in, const int* in_sizes, int n_in,
                              void* d_out, int out_size, void* d_ws, size_t ws_size,
                              hipStream_t stream) {
    const float* x   = (const float*)d_in[0];
    const int*   ei  = (const int*)d_in[1];
    const float* W1  = (const float*)d_in[2];
    const float* b1  = (const float*)d_in[3];
    const float* W2  = (const float*)d_in[4];
    const float* b2  = (const float*)d_in[5];
    const float* W3  = (const float*)d_in[6];
    const float* b3  = (const float*)d_in[7];
    const float* Wfc = (const float*)d_in[8];
    const float* bfc = (const float*)d_in[9];
    float* out = (float*)d_out;

    const int N = N_NODES_C;
    const int E = N_EDGES_C;
    const int* src = ei;
    const int* dst = ei + E;

    // workspace carve-up (16B aligned)
    float* dinv    = (float*)d_ws;                    // N
    int*   bcur    = (int*)(dinv + N);                // 128 (zeroed)
    int*   bOff    = bcur + 128;                      // 128
    int*   row_ptr = bOff + 128;                      // N+4
    int*   col     = row_ptr + N + 4;                 // E
    float* hs      = (float*)(col + E);               // N*64
    float* act     = hs + (size_t)N * HID_C;          // N*64
    int*   pairs   = (int*)hs;                        // NBUCK*BCAP ints = 14.5MB, dead before hs written

    int gN4  = (N + 3) / 4;
    int gNF  = (N * HID_C + 255) / 256;
    int gBK  = (E + TILE - 1) / TILE;                 // 1563
    int gFC  = (N * N_CLS_C + 255) / 256;

    // ---- CSR build (+ dinv), zero per-edge global atomics ----
    hipMemsetAsync(bcur, 0, 128 * sizeof(int), stream);
    k_bucket<<<gBK, 256, 0, stream>>>(src, dst, bcur, pairs, E);
    k_bscan<<<1, 128, 0, stream>>>(bcur, bOff, NBUCK);
    k_build<<<NBUCK, 1024, 0, stream>>>(pairs, bcur, bOff, row_ptr, dinv, col);

    // ---- layer 1: x(10) -> act ----
    k_mm_scale<IN_F_C><<<gNF, 256, 0, stream>>>(x, W1, dinv, hs, N);
    k_gather<<<gN4, 256, 0, stream>>>(row_ptr, col, hs, dinv, b1, act, N);

    // ---- layer 2 ----
    k_mm_scale<HID_C><<<gNF, 256, 0, stream>>>(act, W2, dinv, hs, N);
    k_gather<<<gN4, 256, 0, stream>>>(row_ptr, col, hs, dinv, b2, act, N);

    // ---- layer 3 ----
    k_mm_scale<HID_C><<<gNF, 256, 0, stream>>>(act, W3, dinv, hs, N);
    k_gather<<<gN4, 256, 0, stream>>>(row_ptr, col, hs, dinv, b3, act, N);

    // ---- final FC ----
    k_fc<<<gFC, 256, 0, stream>>>(act, Wfc, bfc, out, N);
}

// Round 6
// 580.852 us; speedup vs baseline: 4.0879x; 1.3089x over previous
//
#include <hip/hip_runtime.h>
#include <hip/hip_fp16.h>

#define N_NODES_C 100000
#define N_EDGES_C 3200000
#define IN_F_C 10
#define HID_C 64
#define N_CLS_C 10
#define NEG_SLOPE_C 0.01f

#define NBUCK 98        // ceil(100000/1024); bucket = dst >> 10
#define BCAP  36864     // mean 32768, sigma ~180 -> +22 sigma headroom
#define TILE  2048      // edges per block in k_bucket (256 thr x 8)

// ---------------- pass 1: bucket partition, packed pairs, no global atomics per edge ----------------
__global__ __launch_bounds__(256) void k_bucket(const int* __restrict__ src,
                                                const int* __restrict__ dst,
                                                int* __restrict__ bcur,
                                                int* __restrict__ pairs, int E) {
    __shared__ int lcnt[NBUCK];
    __shared__ int gbase[NBUCK];
    const int t = threadIdx.x;
    for (int i = t; i < NBUCK; i += 256) lcnt[i] = 0;
    __syncthreads();
    const int base = blockIdx.x * TILE;
    int p[8], r[8], nb[8];
#pragma unroll
    for (int i = 0; i < 8; ++i) {
        int e = base + t + i * 256;
        if (e < E) {
            int s = src[e], d = dst[e];
            int b = d >> 10;
            nb[i] = b;
            p[i] = (s << 10) | (d & 1023);   // src<2^17, local dst<2^10
            r[i] = atomicAdd(&lcnt[b], 1);   // tile-local rank (LDS)
        }
    }
    __syncthreads();
    for (int i = t; i < NBUCK; i += 256)
        gbase[i] = lcnt[i] ? atomicAdd(&bcur[i], lcnt[i]) : 0;
    __syncthreads();
#pragma unroll
    for (int i = 0; i < 8; ++i) {
        int e = base + t + i * 256;
        if (e < E) {
            int pos = gbase[nb[i]] + r[i];
            if (pos < BCAP) pairs[nb[i] * BCAP + pos] = p[i];
        }
    }
}

// ---------------- tiny scan of 98 bucket sizes -> bucket base offsets ----------------
__global__ __launch_bounds__(128) void k_bscan(const int* __restrict__ bcur,
                                               int* __restrict__ bOff, int nbk) {
    __shared__ int s[128];
    int t = threadIdx.x;
    int v = (t < nbk) ? bcur[t] : 0;
    s[t] = v;
    __syncthreads();
    for (int off = 1; off < 128; off <<= 1) {
        int u = (t >= off) ? s[t - off] : 0;
        __syncthreads();
        s[t] += u;
        __syncthreads();
    }
    if (t < nbk) bOff[t] = s[t] - v;
}

// ---------------- pass 2: per-bucket hist + scan + row_ptr/dinv + placement, all LDS-local ----------------
__global__ __launch_bounds__(1024) void k_build(const int* __restrict__ pairs,
                                                const int* __restrict__ bcur,
                                                const int* __restrict__ bOff,
                                                int* __restrict__ row_ptr,
                                                float* __restrict__ dinv,
                                                int* __restrict__ col) {
    __shared__ int hist[1024];
    __shared__ int sm[1024];
    const int b = blockIdx.x;
    const int t = threadIdx.x;
    const int n = min(bcur[b], BCAP);
    const int base = bOff[b];
    const int* pp = pairs + b * BCAP;

    hist[t] = 0;
    __syncthreads();
    for (int i = t; i < n; i += 1024) atomicAdd(&hist[pp[i] & 1023], 1);
    __syncthreads();
    int c = hist[t];
    sm[t] = c;
    __syncthreads();
    for (int off = 1; off < 1024; off <<= 1) {
        int u = (t >= off) ? sm[t - off] : 0;
        __syncthreads();
        sm[t] += u;
        __syncthreads();
    }
    int rp = base + sm[t] - c;
    int gnode = (b << 10) + t;
    if (gnode < N_NODES_C) {
        row_ptr[gnode] = rp;
        dinv[gnode] = rsqrtf((float)(c + 1));
        if (gnode == N_NODES_C - 1) row_ptr[N_NODES_C] = rp + c;
    }
    __syncthreads();
    sm[t] = rp;
    __syncthreads();
    for (int i = t; i < n; i += 1024) {
        int p = pp[i];
        int idx = atomicAdd(&sm[p & 1023], 1);
        col[idx] = p >> 10;
    }
}

// ---------------- matmul + dinv scale -> fp16 hs ----------------
template <int K>
__global__ __launch_bounds__(256) void k_mm_scale16(const float* __restrict__ hin,
                                                    const float* __restrict__ W,
                                                    const float* __restrict__ dinv,
                                                    __half* __restrict__ hs, int n) {
    __shared__ float Ws[K * HID_C];
    for (int i = threadIdx.x; i < K * HID_C; i += blockDim.x) Ws[i] = W[i];
    __syncthreads();
    int total = n * HID_C;
    for (int t = blockIdx.x * blockDim.x + threadIdx.x; t < total; t += gridDim.x * blockDim.x) {
        int nn = t >> 6;
        int f  = t & 63;
        const float* row = hin + (long long)nn * K;
        float s = 0.f;
#pragma unroll
        for (int k = 0; k < K; ++k) s += row[k] * Ws[k * HID_C + f];
        hs[t] = __float2half(s * dinv[nn]);
    }
}

// ---------------- fused gather (fp16 rows, 2 edges/wave-step) + epilogue ----------------
__global__ __launch_bounds__(256) void k_gather16(const int* __restrict__ row_ptr,
                                                  const int* __restrict__ col,
                                                  const __half2* __restrict__ hs,   // [n][32]
                                                  const float* __restrict__ dinv,
                                                  const float* __restrict__ b,
                                                  float* __restrict__ out, int n) {
    const int lane = threadIdx.x & 63;
    const int half = lane >> 5;          // which edge of the pair
    const int fl   = lane & 31;          // feature-pair index (2 features)
    const int d = (blockIdx.x << 2) + (threadIdx.x >> 6);   // 4 waves / block
    if (d >= n) return;
    const int beg = row_ptr[d];
    const int end = row_ptr[d + 1];
    float2 acc = make_float2(0.f, 0.f);
    if (!half) {                          // self loop on half 0
        float2 v = __half22float2(hs[(d << 5) + fl]);
        acc.x = v.x; acc.y = v.y;
    }
    int e = beg;
    for (; e + 7 < end; e += 8) {         // 8 edges per iter (4 loads in flight/lane)
        int i0 = e + half, i1 = e + 2 + half, i2 = e + 4 + half, i3 = e + 6 + half;
        int s0 = col[i0], s1 = col[i1], s2 = col[i2], s3 = col[i3];
        float2 v0 = __half22float2(hs[(s0 << 5) + fl]);
        float2 v1 = __half22float2(hs[(s1 << 5) + fl]);
        float2 v2 = __half22float2(hs[(s2 << 5) + fl]);
        float2 v3 = __half22float2(hs[(s3 << 5) + fl]);
        acc.x += v0.x + v1.x + v2.x + v3.x;
        acc.y += v0.y + v1.y + v2.y + v3.y;
    }
    for (; e < end; e += 2) {
        int i = e + half;
        if (i < end) {
            float2 v = __half22float2(hs[(col[i] << 5) + fl]);
            acc.x += v.x; acc.y += v.y;
        }
    }
    // combine the two half-wave partials
    acc.x += __shfl_xor(acc.x, 32, 64);
    acc.y += __shfl_xor(acc.y, 32, 64);
    if (!half) {
        float di = dinv[d];
        float2 bb = ((const float2*)b)[fl];
        float vx = acc.x * di + bb.x;
        float vy = acc.y * di + bb.y;
        vx = vx > 0.f ? vx : NEG_SLOPE_C * vx;
        vy = vy > 0.f ? vy : NEG_SLOPE_C * vy;
        ((float2*)out)[(d << 5) + fl] = make_float2(vx, vy);
    }
}

// ---------------- final FC ----------------
__global__ __launch_bounds__(256) void k_fc(const float* __restrict__ h,
                                            const float* __restrict__ W,
                                            const float* __restrict__ b,
                                            float* __restrict__ out, int n) {
    __shared__ float Ws[HID_C * N_CLS_C];
    for (int i = threadIdx.x; i < HID_C * N_CLS_C; i += blockDim.x) Ws[i] = W[i];
    __syncthreads();
    int total = n * N_CLS_C;
    for (int t = blockIdx.x * blockDim.x + threadIdx.x; t < total; t += gridDim.x * blockDim.x) {
        int nn = t / N_CLS_C;
        int c  = t - nn * N_CLS_C;
        const float* row = h + (long long)nn * HID_C;
        float s = b[c];
#pragma unroll
        for (int k = 0; k < HID_C; ++k) s += row[k] * Ws[k * N_CLS_C + c];
        out[t] = s;
    }
}

extern "C" void kernel_launch(void* const* d_in, const int* in_sizes, int n_in,
                              void* d_out, int out_size, void* d_ws, size_t ws_size,
                              hipStream_t stream) {
    const float* x   = (const float*)d_in[0];
    const int*   ei  = (const int*)d_in[1];
    const float* W1  = (const float*)d_in[2];
    const float* b1  = (const float*)d_in[3];
    const float* W2  = (const float*)d_in[4];
    const float* b2  = (const float*)d_in[5];
    const float* W3  = (const float*)d_in[6];
    const float* b3  = (const float*)d_in[7];
    const float* Wfc = (const float*)d_in[8];
    const float* bfc = (const float*)d_in[9];
    float* out = (float*)d_out;

    const int N = N_NODES_C;
    const int E = N_EDGES_C;
    const int* src = ei;
    const int* dst = ei + E;

    // workspace carve-up (16B aligned)
    float* dinv    = (float*)d_ws;                    // N
    int*   bcur    = (int*)(dinv + N);                // 128 (zeroed)
    int*   bOff    = bcur + 128;                      // 128
    int*   row_ptr = bOff + 128;                      // N+4
    int*   col     = row_ptr + N + 4;                 // E
    __half* hs16   = (__half*)(col + E);              // N*64 halves = 12.8 MB
    int*   pairs   = (int*)hs16;                      // NBUCK*BCAP ints = 14.45 MB (aliases hs16+)
    // act starts after the LARGER of (hs16, pairs) regions:
    float* act     = (float*)((char*)hs16 + (size_t)NBUCK * BCAP * sizeof(int)); // N*64 floats

    int gN4  = (N + 3) / 4;
    int gNF  = (N * HID_C + 255) / 256;
    int gBK  = (E + TILE - 1) / TILE;
    int gFC  = (N * N_CLS_C + 255) / 256;

    // ---- CSR build (+ dinv), zero per-edge global atomics ----
    hipMemsetAsync(bcur, 0, 128 * sizeof(int), stream);
    k_bucket<<<gBK, 256, 0, stream>>>(src, dst, bcur, pairs, E);
    k_bscan<<<1, 128, 0, stream>>>(bcur, bOff, NBUCK);
    k_build<<<NBUCK, 1024, 0, stream>>>(pairs, bcur, bOff, row_ptr, dinv, col);

    // ---- layer 1: x(10) -> act ----
    k_mm_scale16<IN_F_C><<<gNF, 256, 0, stream>>>(x, W1, dinv, hs16, N);
    k_gather16<<<gN4, 256, 0, stream>>>(row_ptr, col, (const __half2*)hs16, dinv, b1, act, N);

    // ---- layer 2 ----
    k_mm_scale16<HID_C><<<gNF, 256, 0, stream>>>(act, W2, dinv, hs16, N);
    k_gather16<<<gN4, 256, 0, stream>>>(row_ptr, col, (const __half2*)hs16, dinv, b2, act, N);

    // ---- layer 3 ----
    k_mm_scale16<HID_C><<<gNF, 256, 0, stream>>>(act, W3, dinv, hs16, N);
    k_gather16<<<gN4, 256, 0, stream>>>(row_ptr, col, (const __half2*)hs16, dinv, b3, act, N);

    // ---- final FC ----
    k_fc<<<gFC, 256, 0, stream>>>(act, Wfc, bfc, out, N);
}

// Round 7
// 446.012 us; speedup vs baseline: 5.3238x; 1.3023x over previous
//
#include <hip/hip_runtime.h>
#include <hip/hip_fp16.h>

#define N_NODES_C 100000
#define N_EDGES_C 3200000
#define IN_F_C 10
#define HID_C 64
#define N_CLS_C 10
#define NEG_SLOPE_C 0.01f

#define NBUCK 98        // ceil(100000/1024); bucket = dst >> 10
#define BCAP  36864     // mean 32768, sigma ~180 -> +22 sigma headroom
#define TILE  2048      // edges per block in k_bucket (256 thr x 8)

// ---------------- pass 1: bucket partition, packed pairs, no global atomics per edge ----------------
__global__ __launch_bounds__(256) void k_bucket(const int* __restrict__ src,
                                                const int* __restrict__ dst,
                                                int* __restrict__ bcur,
                                                int* __restrict__ pairs, int E) {
    __shared__ int lcnt[NBUCK];
    __shared__ int gbase[NBUCK];
    const int t = threadIdx.x;
    for (int i = t; i < NBUCK; i += 256) lcnt[i] = 0;
    __syncthreads();
    const int base = blockIdx.x * TILE;
    int p[8], r[8], nb[8];
#pragma unroll
    for (int i = 0; i < 8; ++i) {
        int e = base + t + i * 256;
        if (e < E) {
            int s = src[e], d = dst[e];
            int b = d >> 10;
            nb[i] = b;
            p[i] = (s << 10) | (d & 1023);   // src<2^17, local dst<2^10
            r[i] = atomicAdd(&lcnt[b], 1);   // tile-local rank (LDS)
        }
    }
    __syncthreads();
    for (int i = t; i < NBUCK; i += 256)
        gbase[i] = lcnt[i] ? atomicAdd(&bcur[i], lcnt[i]) : 0;
    __syncthreads();
#pragma unroll
    for (int i = 0; i < 8; ++i) {
        int e = base + t + i * 256;
        if (e < E) {
            int pos = gbase[nb[i]] + r[i];
            if (pos < BCAP) pairs[nb[i] * BCAP + pos] = p[i];
        }
    }
}

// ---------------- tiny scan of 98 bucket sizes -> bucket base offsets ----------------
__global__ __launch_bounds__(128) void k_bscan(const int* __restrict__ bcur,
                                               int* __restrict__ bOff, int nbk) {
    __shared__ int s[128];
    int t = threadIdx.x;
    int v = (t < nbk) ? bcur[t] : 0;
    s[t] = v;
    __syncthreads();
    for (int off = 1; off < 128; off <<= 1) {
        int u = (t >= off) ? s[t - off] : 0;
        __syncthreads();
        s[t] += u;
        __syncthreads();
    }
    if (t < nbk) bOff[t] = s[t] - v;
}

// ---------------- pass 2: per-bucket hist + scan + row_ptr/dinv + placement, all LDS-local ----------------
__global__ __launch_bounds__(1024) void k_build(const int* __restrict__ pairs,
                                                const int* __restrict__ bcur,
                                                const int* __restrict__ bOff,
                                                int* __restrict__ row_ptr,
                                                float* __restrict__ dinv,
                                                int* __restrict__ col) {
    __shared__ int hist[1024];
    __shared__ int sm[1024];
    const int b = blockIdx.x;
    const int t = threadIdx.x;
    const int n = min(bcur[b], BCAP);
    const int base = bOff[b];
    const int* pp = pairs + b * BCAP;

    hist[t] = 0;
    __syncthreads();
    for (int i = t; i < n; i += 1024) atomicAdd(&hist[pp[i] & 1023], 1);
    __syncthreads();
    int c = hist[t];
    sm[t] = c;
    __syncthreads();
    for (int off = 1; off < 1024; off <<= 1) {
        int u = (t >= off) ? sm[t - off] : 0;
        __syncthreads();
        sm[t] += u;
        __syncthreads();
    }
    int rp = base + sm[t] - c;
    int gnode = (b << 10) + t;
    if (gnode < N_NODES_C) {
        row_ptr[gnode] = rp;
        dinv[gnode] = rsqrtf((float)(c + 1));
        if (gnode == N_NODES_C - 1) row_ptr[N_NODES_C] = rp + c;
    }
    __syncthreads();
    sm[t] = rp;
    __syncthreads();
    for (int i = t; i < n; i += 1024) {
        int p = pp[i];
        int idx = atomicAdd(&sm[p & 1023], 1);
        col[idx] = p >> 10;
    }
}

// ---------------- layer-1 transform: hs[n,f] = (x[n,:10] @ W1)[f] * dinv[n], one thread per (node, f-quad) ----------------
__global__ __launch_bounds__(256) void k_mm0(const float* __restrict__ x,
                                             const float* __restrict__ W,
                                             const float* __restrict__ dinv,
                                             __half* __restrict__ hs, int n) {
    __shared__ float4 W4[IN_F_C * 16];           // W4[k*16+f4] = W[k][4f4..4f4+3]
    const int t = threadIdx.x;
    for (int i = t; i < IN_F_C * 16; i += 256) {
        int k = i >> 4, f4 = i & 15;
        W4[i] = ((const float4*)(W + k * HID_C))[f4];
    }
    __syncthreads();
    int idx = blockIdx.x * 256 + t;              // node*16 + f4
    if (idx >= n * 16) return;
    int nn = idx >> 4, f4 = idx & 15;
    const float* row = x + nn * IN_F_C;
    float4 acc = make_float4(0.f, 0.f, 0.f, 0.f);
#pragma unroll
    for (int k = 0; k < IN_F_C; ++k) {
        float xv = row[k];
        float4 w = W4[k * 16 + f4];
        acc.x += xv * w.x; acc.y += xv * w.y; acc.z += xv * w.z; acc.w += xv * w.w;
    }
    float di = dinv[nn];
    __half2 h0 = __floats2half2_rn(acc.x * di, acc.y * di);
    __half2 h1 = __floats2half2_rn(acc.z * di, acc.w * di);
    ((__half2*)hs)[(nn << 5) + 2 * f4]     = h0;
    ((__half2*)hs)[(nn << 5) + 2 * f4 + 1] = h1;
}

// ---------------- fused gather + epilogue + NEXT-layer transform ----------------
// acc = hs[d] + sum_e hs[col[e]];  act = lrelu(acc*dinv[d] + bias)
// !LAST: hs_next[d][f'] = (act @ Wn)[f'] * dinv[d]   (fp16 out)
//  LAST: out[d][f']     = (act @ Wn)[f'] + bn[f']    (fp32 out)
template <int NEXT_F, bool LAST>
__global__ __launch_bounds__(256) void k_gft(const int* __restrict__ row_ptr,
                                             const int* __restrict__ col,
                                             const __half* __restrict__ hsrc,
                                             const float* __restrict__ dinv,
                                             const float* __restrict__ bias,
                                             const float* __restrict__ Wn,
                                             const float* __restrict__ bn,
                                             void* __restrict__ outp, int n) {
    __shared__ float4 Ws4[16 * NEXT_F];          // Ws4[k4*NEXT_F+f] = Wn[4k4..4k4+3][f]
    __shared__ float rowbuf[4][64];
    const int t = threadIdx.x;
    for (int i = t; i < 16 * NEXT_F; i += 256) {
        int k4 = i / NEXT_F, f = i - k4 * NEXT_F;
        Ws4[i] = make_float4(Wn[(4 * k4 + 0) * NEXT_F + f], Wn[(4 * k4 + 1) * NEXT_F + f],
                             Wn[(4 * k4 + 2) * NEXT_F + f], Wn[(4 * k4 + 3) * NEXT_F + f]);
    }
    __syncthreads();

    const int lane = t & 63;
    const int wid  = t >> 6;
    const int g    = lane >> 4;                  // edge group 0..3
    const int fl   = lane & 15;                  // feature-quad 4fl..4fl+3
    const int d = (blockIdx.x << 2) + wid;
    if (d >= n) return;
    const int beg = row_ptr[d];
    const int end = row_ptr[d + 1];
    const float2* hsv = (const float2*)hsrc;     // 8B = 4 halves per lane

    float4 acc = make_float4(0.f, 0.f, 0.f, 0.f);
    if (g == 0) {                                // self loop
        float2 raw = hsv[(d << 4) + fl];
        float2 a0 = __half22float2(*(__half2*)&raw.x);
        float2 a1 = __half22float2(*(__half2*)&raw.y);
        acc = make_float4(a0.x, a0.y, a1.x, a1.y);
    }
    int e = beg;
    for (; e + 7 < end; e += 8) {                // 8 edges/iter, 2 loads in flight/lane
        int s0 = col[e + g];
        int s1 = col[e + 4 + g];
        float2 r0 = hsv[(s0 << 4) + fl];
        float2 r1 = hsv[(s1 << 4) + fl];
        float2 a0 = __half22float2(*(__half2*)&r0.x);
        float2 a1 = __half22float2(*(__half2*)&r0.y);
        float2 b0 = __half22float2(*(__half2*)&r1.x);
        float2 b1 = __half22float2(*(__half2*)&r1.y);
        acc.x += a0.x + b0.x; acc.y += a0.y + b0.y;
        acc.z += a1.x + b1.x; acc.w += a1.y + b1.y;
    }
    for (; e < end; e += 4) {
        int i = e + g;
        if (i < end) {
            float2 r = hsv[(col[i] << 4) + fl];
            float2 a0 = __half22float2(*(__half2*)&r.x);
            float2 a1 = __half22float2(*(__half2*)&r.y);
            acc.x += a0.x; acc.y += a0.y; acc.z += a1.x; acc.w += a1.y;
        }
    }
    // combine the 4 edge-groups
    acc.x += __shfl_xor(acc.x, 16, 64); acc.y += __shfl_xor(acc.y, 16, 64);
    acc.z += __shfl_xor(acc.z, 16, 64); acc.w += __shfl_xor(acc.w, 16, 64);
    acc.x += __shfl_xor(acc.x, 32, 64); acc.y += __shfl_xor(acc.y, 32, 64);
    acc.z += __shfl_xor(acc.z, 32, 64); acc.w += __shfl_xor(acc.w, 32, 64);

    const float di = dinv[d];
    if (g == 0) {                                // epilogue -> act row in LDS
        float4 bb = ((const float4*)bias)[fl];
        float4 v;
        v.x = acc.x * di + bb.x; v.y = acc.y * di + bb.y;
        v.z = acc.z * di + bb.z; v.w = acc.w * di + bb.w;
        v.x = v.x > 0.f ? v.x : NEG_SLOPE_C * v.x;
        v.y = v.y > 0.f ? v.y : NEG_SLOPE_C * v.y;
        v.z = v.z > 0.f ? v.z : NEG_SLOPE_C * v.z;
        v.w = v.w > 0.f ? v.w : NEG_SLOPE_C * v.w;
        ((float4*)rowbuf[wid])[fl] = v;
    }
    // wave-synchronous LDS: no barrier needed (same wave writes & reads)
    if (lane < NEXT_F) {
        float s = LAST ? bn[lane] : 0.f;
        const float4* rb = (const float4*)rowbuf[wid];
#pragma unroll
        for (int k4 = 0; k4 < 16; ++k4) {
            float4 r4 = rb[k4];
            float4 w4 = Ws4[k4 * NEXT_F + lane];
            s += r4.x * w4.x + r4.y * w4.y + r4.z * w4.z + r4.w * w4.w;
        }
        if (LAST) {
            ((float*)outp)[d * NEXT_F + lane] = s;
        } else {
            ((__half*)outp)[(d << 6) + lane] = __float2half(s * di);
        }
    }
}

extern "C" void kernel_launch(void* const* d_in, const int* in_sizes, int n_in,
                              void* d_out, int out_size, void* d_ws, size_t ws_size,
                              hipStream_t stream) {
    const float* x   = (const float*)d_in[0];
    const int*   ei  = (const int*)d_in[1];
    const float* W1  = (const float*)d_in[2];
    const float* b1  = (const float*)d_in[3];
    const float* W2  = (const float*)d_in[4];
    const float* b2  = (const float*)d_in[5];
    const float* W3  = (const float*)d_in[6];
    const float* b3  = (const float*)d_in[7];
    const float* Wfc = (const float*)d_in[8];
    const float* bfc = (const float*)d_in[9];
    float* out = (float*)d_out;

    const int N = N_NODES_C;
    const int E = N_EDGES_C;
    const int* src = ei;
    const int* dst = ei + E;

    // workspace carve-up (16B aligned)
    float*  dinv    = (float*)d_ws;                   // N
    int*    bcur    = (int*)(dinv + N);               // 128 (zeroed)
    int*    bOff    = bcur + 128;                     // 128
    int*    row_ptr = bOff + 128;                     // N+4
    int*    col     = row_ptr + N + 4;                // E
    int*    pairs   = col + E;                        // NBUCK*BCAP ints = 14.45 MB
    __half* hsA     = (__half*)pairs;                 // N*64 halves = 12.8 MB (aliases pairs; pairs dead by k_mm0)
    __half* hsB     = (__half*)(pairs + (size_t)NBUCK * BCAP);   // N*64 halves

    int gN4  = (N + 3) / 4;                           // 25000 blocks, 4 waves each
    int gM0  = (N * 16 + 255) / 256;                  // 6250
    int gBK  = (E + TILE - 1) / TILE;                 // 1563

    // ---- CSR build (+ dinv), zero per-edge global atomics ----
    hipMemsetAsync(bcur, 0, 128 * sizeof(int), stream);
    k_bucket<<<gBK, 256, 0, stream>>>(src, dst, bcur, pairs, E);
    k_bscan<<<1, 128, 0, stream>>>(bcur, bOff, NBUCK);
    k_build<<<NBUCK, 1024, 0, stream>>>(pairs, bcur, bOff, row_ptr, dinv, col);

    // ---- layer 1 transform: x @ W1 * dinv -> hsA ----
    k_mm0<<<gM0, 256, 0, stream>>>(x, W1, dinv, hsA, N);

    // ---- fused gather+epilogue+transform chain ----
    k_gft<HID_C, false><<<gN4, 256, 0, stream>>>(row_ptr, col, hsA, dinv, b1, W2, nullptr, hsB, N);
    k_gft<HID_C, false><<<gN4, 256, 0, stream>>>(row_ptr, col, hsB, dinv, b2, W3, nullptr, hsA, N);
    k_gft<N_CLS_C, true><<<gN4, 256, 0, stream>>>(row_ptr, col, hsA, dinv, b3, Wfc, bfc, out, N);
}